// Round 2
// baseline (241.487 us; speedup 1.0000x reference)
//
#include <hip/hip_runtime.h>
#include <math.h>

// Problem sizes (fixed by setup_inputs)
constexpr int BATCH = 64;
constexpr int IN    = 1024;
constexpr int NN    = 2048;   // num_neurons
constexpr int OUTF  = 1024;

constexpr float INV2PI = 0.15915494309189535f;  // 1/(2*pi)
constexpr float SQRT2  = 1.4142135623730951f;

// sin_t + cos_t = sqrt(2)*sin(theta + pi/4); reference LUT-quantizes theta to
// 2pi/4096 steps. We drop the quantization (|err| <= sqrt2*pi/4096 ~ 1.1e-3
// per element -> ~8 absmax on the output vs threshold 26.7), so each element
// is ONE fma + ONE v_sin: a = x*(rcp(1+|W|)/2pi) + (B/2pi + 1/8) [revolutions].

// Butterfly transpose-reduction with COMPILE-TIME trip counts.
template<int M>
__device__ __forceinline__ void butterfly(float* acc, int lane) {
    const bool hi = (lane & M) != 0;
#pragma unroll
    for (int j = 0; j < M; ++j) {
        const float send = hi ? acc[j] : acc[j + M];
        const float recv = __shfl_xor(send, M, 64);
        acc[j] = (hi ? acc[j + M] : acc[j]) + recv;
    }
    if constexpr (M > 1) butterfly<M / 2>(acc, lane);
}

// ---------------- Stage 1: interference ----------------
// ROUND-1 POST-MORTEM: 2n x 32b per wave needed acc[64] (+48 operand regs)
// -> spilled at VGPR=128 -> 350MB of scratch HBM traffic -> 107us. The
// LDS-economy idea (one x read feeds 2 neurons) survives; the acc budget
// doesn't. This version: wave = 2 neurons x 16 batches -> acc[32]; block =
// 16 waves (1024 thr) = 8 neurons x 64 batches so W/B are still fetched
// ONCE per neuron-octet (no quarter-refetch). LDS: all 64 x-rows staged,
// 2 x 64KB double buffer -> 1 block/CU, 4 waves/SIMD.
// Live VGPRs: acc 32 + iv/bs 16 + wn/bn 16 + xv/sin/addr ~26  ->  ~90 < 128.
// Pipe math per SIMD/chunk: sin 4w x 128 x 8cyc = 4096 cyc (roof);
// LDS/CU 256 x 12 = 3072 cyc; HBM 17MB unique = 2.7us. Floor ~7us.

__global__ __launch_bounds__(1024)
__attribute__((amdgpu_waves_per_eu(4, 4)))
void k_interf(const float* __restrict__ x, const float* __restrict__ W,
              const float* __restrict__ B, float* __restrict__ part) {
    __shared__ float xs[2][64 * 256];   // double buffer, 2 x 64KB

    const int tid  = threadIdx.x;
    const int lane = tid & 63;
    const int wv   = __builtin_amdgcn_readfirstlane(tid >> 6);   // 0..15
    const int np   = wv & 3;                 // neuron-pair within block
    const int q    = wv >> 2;                // batch quarter 0..3
    const int n0   = blockIdx.x * 8 + np * 2;  // 256 blocks x 8 neurons
    const int b0   = q * 16;

#define STAGE(KC, P)                                                           \
    {                                                                          \
        _Pragma("unroll")                                                      \
        for (int rr = 0; rr < 4; ++rr) {                                       \
            const int r = wv * 4 + rr;  /* wave-uniform LDS base, covers 0..63 */ \
            __builtin_amdgcn_global_load_lds(                                  \
                (const __attribute__((address_space(1))) unsigned int*)        \
                    (x + (size_t)r * IN + (KC) * 256 + 4 * lane),              \
                (__attribute__((address_space(3))) unsigned int*)              \
                    &xs[(P)][r * 256],                                         \
                16, 0, 0);                                                     \
        }                                                                      \
    }

    // chunk-0 W/B raw loads (converted to iv/bs below, buffer reused for
    // the next chunk's prefetch so only ONE raw copy is ever live)
    float4 wn[2], bn[2];
#pragma unroll
    for (int j = 0; j < 2; ++j) {
        wn[j] = *(const float4*)&W[(size_t)(n0 + j) * IN + 4 * lane];
        bn[j] = *(const float4*)&B[(size_t)(n0 + j) * IN + 4 * lane];
    }

    float acc[32];   // acc[j*16+bb]: neuron j, batch b0+bb — indices static
#pragma unroll
    for (int i = 0; i < 32; ++i) acc[i] = 0.0f;

    STAGE(0, 0);

    // fold chunk-0 per-(n,k) math: a = x*iv + bs (revolutions, includes +1/8)
    float4 iv[2], bs[2];
#pragma unroll
    for (int j = 0; j < 2; ++j) {
        iv[j].x = INV2PI * __builtin_amdgcn_rcpf(1.0f + fabsf(wn[j].x));
        iv[j].y = INV2PI * __builtin_amdgcn_rcpf(1.0f + fabsf(wn[j].y));
        iv[j].z = INV2PI * __builtin_amdgcn_rcpf(1.0f + fabsf(wn[j].z));
        iv[j].w = INV2PI * __builtin_amdgcn_rcpf(1.0f + fabsf(wn[j].w));
        bs[j].x = fmaf(bn[j].x, INV2PI, 0.125f);
        bs[j].y = fmaf(bn[j].y, INV2PI, 0.125f);
        bs[j].z = fmaf(bn[j].z, INV2PI, 0.125f);
        bs[j].w = fmaf(bn[j].w, INV2PI, 0.125f);
    }
    __syncthreads();   // chunk 0 staged

#pragma unroll 1       // keep code size small; body is bb-unrolled
    for (int kc = 0; kc < 4; ++kc) {
        const int p = kc & 1;

        if (kc < 3) {   // prefetch next W/B chunk (regs) + next x chunk (LDS)
#pragma unroll
            for (int j = 0; j < 2; ++j) {
                wn[j] = *(const float4*)&W[(size_t)(n0 + j) * IN + (kc + 1) * 256 + 4 * lane];
                bn[j] = *(const float4*)&B[(size_t)(n0 + j) * IN + (kc + 1) * 256 + 4 * lane];
            }
            STAGE(kc + 1, 1 - p);
        }

#pragma unroll   // MUST be full: dynamic acc idx -> scratch
        for (int bb = 0; bb < 16; ++bb) {
            const float4 xv = *(const float4*)&xs[p][(b0 + bb) * 256 + 4 * lane];
#pragma unroll
            for (int j = 0; j < 2; ++j) {   // one LDS read serves BOTH neurons
                const float a0 = fmaf(xv.x, iv[j].x, bs[j].x);
                const float a1 = fmaf(xv.y, iv[j].y, bs[j].y);
                const float a2 = fmaf(xv.z, iv[j].z, bs[j].z);
                const float a3 = fmaf(xv.w, iv[j].w, bs[j].w);
                const float t0 = __builtin_amdgcn_sinf(a0);   // sin(2*pi*a)
                const float t1 = __builtin_amdgcn_sinf(a1);
                const float t2 = __builtin_amdgcn_sinf(a2);
                const float t3 = __builtin_amdgcn_sinf(a3);
                acc[j * 16 + bb] += (t0 + t1) + (t2 + t3);
            }
        }
        __syncthreads();   // frees buf p, drains prefetch

        if (kc < 3) {      // convert prefetched raw W/B in place
#pragma unroll
            for (int j = 0; j < 2; ++j) {
                iv[j].x = INV2PI * __builtin_amdgcn_rcpf(1.0f + fabsf(wn[j].x));
                iv[j].y = INV2PI * __builtin_amdgcn_rcpf(1.0f + fabsf(wn[j].y));
                iv[j].z = INV2PI * __builtin_amdgcn_rcpf(1.0f + fabsf(wn[j].z));
                iv[j].w = INV2PI * __builtin_amdgcn_rcpf(1.0f + fabsf(wn[j].w));
                bs[j].x = fmaf(bn[j].x, INV2PI, 0.125f);
                bs[j].y = fmaf(bn[j].y, INV2PI, 0.125f);
                bs[j].z = fmaf(bn[j].z, INV2PI, 0.125f);
                bs[j].w = fmaf(bn[j].w, INV2PI, 0.125f);
            }
        }
    }
#undef STAGE

    // transpose-reduce 32 values over 64 lanes:
    // lane l (<32) ends with acc index l: j = l>>4, bb = l&15
#pragma unroll
    for (int j = 0; j < 32; ++j) acc[j] += __shfl_xor(acc[j], 32, 64);
    butterfly<16>(acc, lane);

    if (lane < 32)
        part[(size_t)(b0 + (lane & 15)) * NN + n0 + (lane >> 4)] = acc[0] * SQRT2;
}

// ---------------- Stage 2: projection ----------------
// out[b][o] = sum_n part[b][n] * ow[o][n].  Register outer-product, 8o x 8b
// per wave with SCALAR accumulators; only ONE w-row float4 live at a time:
// live regs = acc 64 + vrow 32 + wo 4 + addr ~10 = ~110.  __launch_bounds__
// (256,1) gives the full register budget (grid is 1024 waves over 1024 SIMDs,
// occupancy beyond 1 wave/SIMD is irrelevant).  L2 traffic 128MB -> ~3.7us.

__global__ __launch_bounds__(256, 1)
void k_proj(const float* __restrict__ part, const float* __restrict__ ow,
            float* __restrict__ out) {
    const int tid  = threadIdx.x;
    const int lane = tid & 63;
    const int wv   = __builtin_amdgcn_readfirstlane(tid >> 6);
    const int wid  = blockIdx.x * 4 + wv;        // 0..1023
    const int o0   = (wid & 127) * 8;            // 128 o-tiles x 8
    const int b0   = (wid >> 7) * 8;             // 8 b-tiles x 8

    float acc[64];   // acc[o*8+b]
#pragma unroll
    for (int i = 0; i < 64; ++i) acc[i] = 0.0f;

#pragma unroll 1
    for (int it = 0; it < NN / 256; ++it) {      // 8 slabs of 256 n
        const int nb = it * 256 + lane * 4;
        float4 vrow[8];
#pragma unroll
        for (int b = 0; b < 8; ++b)
            vrow[b] = *(const float4*)&part[(size_t)(b0 + b) * NN + nb];
#pragma unroll
        for (int o = 0; o < 8; ++o) {
            const float4 wo = *(const float4*)&ow[(size_t)(o0 + o) * NN + nb];
#pragma unroll
            for (int b = 0; b < 8; ++b) {
                float s = acc[o * 8 + b];
                s = fmaf(wo.x, vrow[b].x, s);
                s = fmaf(wo.y, vrow[b].y, s);
                s = fmaf(wo.z, vrow[b].z, s);
                s = fmaf(wo.w, vrow[b].w, s);
                acc[o * 8 + b] = s;
            }
        }
    }

    // full 64-lane butterfly: lane l ends with acc[l]'s total
    butterfly<32>(acc, lane);

    // l = o*8+b  ->  o = lane>>3, b = lane&7
    out[(size_t)(b0 + (lane & 7)) * OUTF + o0 + (lane >> 3)] = acc[0];
}

extern "C" void kernel_launch(void* const* d_in, const int* in_sizes, int n_in,
                              void* d_out, int out_size, void* d_ws, size_t ws_size,
                              hipStream_t stream) {
    const float* x  = (const float*)d_in[0];
    const float* W  = (const float*)d_in[1];
    const float* B  = (const float*)d_in[2];
    const float* ow = (const float*)d_in[3];
    float* out  = (float*)d_out;
    float* part = (float*)d_ws;    // 512 KB, [b][n]

    k_interf<<<dim3(256), dim3(1024), 0, stream>>>(x, W, B, part);
    k_proj  <<<dim3(256), dim3(256),  0, stream>>>(part, ow, out);
}

// Round 3
// 238.945 us; speedup vs baseline: 1.0106x; 1.0106x over previous
//
#include <hip/hip_runtime.h>
#include <math.h>

// Problem sizes (fixed by setup_inputs)
constexpr int BATCH = 64;
constexpr int IN    = 1024;
constexpr int NN    = 2048;   // num_neurons
constexpr int OUTF  = 1024;

constexpr float INV2PI = 0.15915494309189535f;  // 1/(2*pi)
constexpr float SQRT2  = 1.4142135623730951f;

// sin_t + cos_t = sqrt(2)*sin(theta + pi/4); reference LUT-quantizes theta to
// 2pi/4096 steps. We drop the quantization (|err| <= sqrt2*pi/4096 ~ 1.1e-3
// per element -> ~8 absmax on the output vs threshold 26.7), so each element
// is ONE fma + ONE v_sin: a = x*(rcp(1+|W|)/2pi) + (B/2pi + 1/8) [revolutions].

// Butterfly transpose-reduction with COMPILE-TIME trip counts.
template<int M>
__device__ __forceinline__ void butterfly(float* acc, int lane) {
    const bool hi = (lane & M) != 0;
#pragma unroll
    for (int j = 0; j < M; ++j) {
        const float send = hi ? acc[j] : acc[j + M];
        const float recv = __shfl_xor(send, M, 64);
        acc[j] = (hi ? acc[j + M] : acc[j]) + recv;
    }
    if constexpr (M > 1) butterfly<M / 2>(acc, lane);
}

// ---------------- Stage 1: interference ----------------
// REGISTER-BUDGET LEDGER (the lesson of rounds 1-2):
//   R1: 256-thr + waves_per_eu(2,2) -> granted 128, needed ~145 -> spill, 107us
//   R2: 1024-thr + waves_per_eu(4,4) -> granted only 64 (!)    -> spill, 134us
//   R0: 512-thr + waves_per_eu(4,4) -> no spill at ~90 live    -> 10-12us
// So: keep the EXACT round-0 envelope (512 thr, 2x32KB LDS, 2 blk/CU) and put
// the nu=2 LDS economy inside it at the SAME acc footprint:
//   wave = 2 neurons x 16 batches -> acc[32]; block = 8 waves = 8n x 32b.
// One ds_read_b128 of x now feeds 8 sins (was 4): LDS/CU/chunk 6144->3072 cyc,
// under the sin roof (4 waves/SIMD x 128 sins x 8 cyc = 4096 cyc/chunk).
// Floor ~6.8us sin-bound + W/B stream (32MB, x2 refetch over batch halves)
// ~5.2us fully overlapped. Live VGPRs: acc 32 + iv/bs 16 + wn/bn 16 + ~25
// temps ~= 90 < 128 (same as R0 -> no spill).

__global__ __launch_bounds__(512)
__attribute__((amdgpu_waves_per_eu(4, 4)))
void k_interf(const float* __restrict__ x, const float* __restrict__ W,
              const float* __restrict__ B, float* __restrict__ part) {
    __shared__ float xs[2][32 * 256];   // double buffer, 2 x 32KB

    const int tid  = threadIdx.x;
    const int lane = tid & 63;
    const int wv   = __builtin_amdgcn_readfirstlane(tid >> 6);   // 0..7
    const int bid  = blockIdx.x;        // 512 blocks
    const int h    = bid & 1;           // batch half (32 rows)
    const int np   = wv & 3;            // neuron-pair within block
    const int hq   = wv >> 2;           // which 16-batch group of the half
    const int n0   = (bid >> 1) * 8 + np * 2;   // 256 n-octets
    const int b0   = hq * 16;           // within the staged 32 rows

    const float* gx = x + (size_t)(h * 32) * IN;   // this block's 32 batch rows

#define STAGE(KC, P)                                                           \
    {                                                                          \
        _Pragma("unroll")                                                      \
        for (int rr = 0; rr < 4; ++rr) {                                       \
            const int r = wv * 4 + rr;  /* wave-uniform LDS base, 0..31 */     \
            __builtin_amdgcn_global_load_lds(                                  \
                (const __attribute__((address_space(1))) unsigned int*)        \
                    (gx + (size_t)r * IN + (KC) * 256 + 4 * lane),             \
                (__attribute__((address_space(3))) unsigned int*)              \
                    &xs[(P)][r * 256],                                         \
                16, 0, 0);                                                     \
        }                                                                      \
    }

    // chunk-0 W/B raw loads (one raw copy live; reused as next-chunk prefetch)
    float4 wn[2], bn[2];
#pragma unroll
    for (int j = 0; j < 2; ++j) {
        wn[j] = *(const float4*)&W[(size_t)(n0 + j) * IN + 4 * lane];
        bn[j] = *(const float4*)&B[(size_t)(n0 + j) * IN + 4 * lane];
    }

    float acc[32];   // acc[j*16+bb]: neuron j, batch b0+bb — indices static
#pragma unroll
    for (int i = 0; i < 32; ++i) acc[i] = 0.0f;

    STAGE(0, 0);

    // fold chunk-0 per-(n,k) math: a = x*iv + bs (revolutions, includes +1/8)
    float4 iv[2], bs[2];
#pragma unroll
    for (int j = 0; j < 2; ++j) {
        iv[j].x = INV2PI * __builtin_amdgcn_rcpf(1.0f + fabsf(wn[j].x));
        iv[j].y = INV2PI * __builtin_amdgcn_rcpf(1.0f + fabsf(wn[j].y));
        iv[j].z = INV2PI * __builtin_amdgcn_rcpf(1.0f + fabsf(wn[j].z));
        iv[j].w = INV2PI * __builtin_amdgcn_rcpf(1.0f + fabsf(wn[j].w));
        bs[j].x = fmaf(bn[j].x, INV2PI, 0.125f);
        bs[j].y = fmaf(bn[j].y, INV2PI, 0.125f);
        bs[j].z = fmaf(bn[j].z, INV2PI, 0.125f);
        bs[j].w = fmaf(bn[j].w, INV2PI, 0.125f);
    }
    __syncthreads();   // chunk 0 staged

#pragma unroll 1       // keep code size small; body is bb-unrolled
    for (int kc = 0; kc < 4; ++kc) {
        const int p = kc & 1;

        if (kc < 3) {   // prefetch next W/B chunk (regs) + next x chunk (LDS)
#pragma unroll
            for (int j = 0; j < 2; ++j) {
                wn[j] = *(const float4*)&W[(size_t)(n0 + j) * IN + (kc + 1) * 256 + 4 * lane];
                bn[j] = *(const float4*)&B[(size_t)(n0 + j) * IN + (kc + 1) * 256 + 4 * lane];
            }
            STAGE(kc + 1, 1 - p);
        }

#pragma unroll   // MUST be full: dynamic acc idx -> scratch
        for (int bb = 0; bb < 16; ++bb) {
            const float4 xv = *(const float4*)&xs[p][(b0 + bb) * 256 + 4 * lane];
#pragma unroll
            for (int j = 0; j < 2; ++j) {   // one LDS read serves BOTH neurons
                const float a0 = fmaf(xv.x, iv[j].x, bs[j].x);
                const float a1 = fmaf(xv.y, iv[j].y, bs[j].y);
                const float a2 = fmaf(xv.z, iv[j].z, bs[j].z);
                const float a3 = fmaf(xv.w, iv[j].w, bs[j].w);
                const float t0 = __builtin_amdgcn_sinf(a0);   // sin(2*pi*a)
                const float t1 = __builtin_amdgcn_sinf(a1);
                const float t2 = __builtin_amdgcn_sinf(a2);
                const float t3 = __builtin_amdgcn_sinf(a3);
                acc[j * 16 + bb] += (t0 + t1) + (t2 + t3);
            }
        }
        __syncthreads();   // frees buf p, drains prefetch

        if (kc < 3) {      // convert prefetched raw W/B in place
#pragma unroll
            for (int j = 0; j < 2; ++j) {
                iv[j].x = INV2PI * __builtin_amdgcn_rcpf(1.0f + fabsf(wn[j].x));
                iv[j].y = INV2PI * __builtin_amdgcn_rcpf(1.0f + fabsf(wn[j].y));
                iv[j].z = INV2PI * __builtin_amdgcn_rcpf(1.0f + fabsf(wn[j].z));
                iv[j].w = INV2PI * __builtin_amdgcn_rcpf(1.0f + fabsf(wn[j].w));
                bs[j].x = fmaf(bn[j].x, INV2PI, 0.125f);
                bs[j].y = fmaf(bn[j].y, INV2PI, 0.125f);
                bs[j].z = fmaf(bn[j].z, INV2PI, 0.125f);
                bs[j].w = fmaf(bn[j].w, INV2PI, 0.125f);
            }
        }
    }
#undef STAGE

    // transpose-reduce 32 values over 64 lanes:
    // lane l (<32) ends with acc index l: j = l>>4, bb = l&15
#pragma unroll
    for (int j = 0; j < 32; ++j) acc[j] += __shfl_xor(acc[j], 32, 64);
    butterfly<16>(acc, lane);

    if (lane < 32)
        part[(size_t)(h * 32 + b0 + (lane & 15)) * NN + n0 + (lane >> 4)] =
            acc[0] * SQRT2;
}

// ---------------- Stage 2: projection ----------------
// out[b][o] = sum_n part[b][n] * ow[o][n].  Register outer-product, 8o x 8b
// per wave with SCALAR accumulators; only ONE w-row float4 live at a time:
// live regs = acc 64 + vrow 32 + wo 4 + addr ~10 = ~110.  __launch_bounds__
// (256,1) gives the full register budget (grid is 1024 waves over 1024 SIMDs).
// L2 traffic 128MB -> ~3.7us; compute 1.7us hidden under it.

__global__ __launch_bounds__(256, 1)
void k_proj(const float* __restrict__ part, const float* __restrict__ ow,
            float* __restrict__ out) {
    const int tid  = threadIdx.x;
    const int lane = tid & 63;
    const int wv   = __builtin_amdgcn_readfirstlane(tid >> 6);
    const int wid  = blockIdx.x * 4 + wv;        // 0..1023
    const int o0   = (wid & 127) * 8;            // 128 o-tiles x 8
    const int b0   = (wid >> 7) * 8;             // 8 b-tiles x 8

    float acc[64];   // acc[o*8+b]
#pragma unroll
    for (int i = 0; i < 64; ++i) acc[i] = 0.0f;

#pragma unroll 1
    for (int it = 0; it < NN / 256; ++it) {      // 8 slabs of 256 n
        const int nb = it * 256 + lane * 4;
        float4 vrow[8];
#pragma unroll
        for (int b = 0; b < 8; ++b)
            vrow[b] = *(const float4*)&part[(size_t)(b0 + b) * NN + nb];
#pragma unroll
        for (int o = 0; o < 8; ++o) {
            const float4 wo = *(const float4*)&ow[(size_t)(o0 + o) * NN + nb];
#pragma unroll
            for (int b = 0; b < 8; ++b) {
                float s = acc[o * 8 + b];
                s = fmaf(wo.x, vrow[b].x, s);
                s = fmaf(wo.y, vrow[b].y, s);
                s = fmaf(wo.z, vrow[b].z, s);
                s = fmaf(wo.w, vrow[b].w, s);
                acc[o * 8 + b] = s;
            }
        }
    }

    // full 64-lane butterfly: lane l ends with acc[l]'s total
    butterfly<32>(acc, lane);

    // l = o*8+b  ->  o = lane>>3, b = lane&7
    out[(size_t)(b0 + (lane & 7)) * OUTF + o0 + (lane >> 3)] = acc[0];
}

extern "C" void kernel_launch(void* const* d_in, const int* in_sizes, int n_in,
                              void* d_out, int out_size, void* d_ws, size_t ws_size,
                              hipStream_t stream) {
    const float* x  = (const float*)d_in[0];
    const float* W  = (const float*)d_in[1];
    const float* B  = (const float*)d_in[2];
    const float* ow = (const float*)d_in[3];
    float* out  = (float*)d_out;
    float* part = (float*)d_ws;    // 512 KB, [b][n]

    k_interf<<<dim3(512), dim3(512), 0, stream>>>(x, W, B, part);
    k_proj  <<<dim3(256), dim3(256), 0, stream>>>(part, ow, out);
}

// Round 4
// 122.684 us; speedup vs baseline: 1.9684x; 1.9476x over previous
//
#include <hip/hip_runtime.h>
#include <math.h>

// Problem sizes (fixed by setup_inputs)
constexpr int BATCH = 64;
constexpr int IN    = 1024;
constexpr int NN    = 2048;   // num_neurons
constexpr int OUTF  = 1024;

constexpr float INV2PI = 0.15915494309189535f;  // 1/(2*pi)
constexpr float SQRT2  = 1.4142135623730951f;

// sin_t + cos_t = sqrt(2)*sin(theta + pi/4); reference LUT-quantizes theta to
// 2pi/4096 steps. We drop the quantization (|err| <= sqrt2*pi/4096 ~ 1.1e-3
// per element -> ~8 absmax on the output vs threshold 26.7), so each element
// is ONE fma + ONE v_sin: a = x*(rcp(1+|W|)/2pi) + (B/2pi + 1/8) [revolutions].

// Butterfly transpose-reduction with COMPILE-TIME trip counts.
template<int M>
__device__ __forceinline__ void butterfly(float* acc, int lane) {
    const bool hi = (lane & M) != 0;
#pragma unroll
    for (int j = 0; j < M; ++j) {
        const float send = hi ? acc[j] : acc[j + M];
        const float recv = __shfl_xor(send, M, 64);
        acc[j] = (hi ? acc[j + M] : acc[j]) + recv;
    }
    if constexpr (M > 1) butterfly<M / 2>(acc, lane);
}

// ---------------- Stage 1: interference ----------------
// REGISTER-BUDGET LEDGER (rounds 1-3, the governing constraint):
//   granted arch-VGPR = 256 / min_waves_per_eu   (NOT 512/min):
//     R1 (2,2) -> 128 granted;  R2+R3 (4,4) -> 64 granted -> hot spill of
//     acc[32] every iteration -> 340MB scratch writes -> 134-142us.
//   R0 survived (4,4)@64 only because its HOT live set was ~50 (prefetchless).
// THIS version: same structure as R3 (wave = 2 neurons x 16 batches, acc[32],
// one ds_read_b128 feeds 8 sins) but waves_per_eu(2,4): min=2 -> 128-reg
// budget, hot live ~90 fits; actual alloc ~100 still allows 4 waves/SIMD
// physically (4 x 100 < 512-slot file; LDS caps at 2 blocks/CU regardless).
// Pipe math/chunk: sin 4w x 128 x 8cyc = 4096 cyc/SIMD (roof, ~6.8us total);
// LDS 16w x 16 x 12 = 3072 cyc/CU (under roof); HBM 35MB ~ 5.5us overlapped.

__global__ __launch_bounds__(512)
__attribute__((amdgpu_waves_per_eu(2, 4)))
void k_interf(const float* __restrict__ x, const float* __restrict__ W,
              const float* __restrict__ B, float* __restrict__ part) {
    __shared__ float xs[2][32 * 256];   // double buffer, 2 x 32KB

    const int tid  = threadIdx.x;
    const int lane = tid & 63;
    const int wv   = __builtin_amdgcn_readfirstlane(tid >> 6);   // 0..7
    const int bid  = blockIdx.x;        // 512 blocks
    const int h    = bid & 1;           // batch half (32 rows)
    const int np   = wv & 3;            // neuron-pair within block
    const int hq   = wv >> 2;           // which 16-batch group of the half
    const int n0   = (bid >> 1) * 8 + np * 2;   // 256 n-octets
    const int b0   = hq * 16;           // within the staged 32 rows

    const float* gx = x + (size_t)(h * 32) * IN;   // this block's 32 batch rows

#define STAGE(KC, P)                                                           \
    {                                                                          \
        _Pragma("unroll")                                                      \
        for (int rr = 0; rr < 4; ++rr) {                                       \
            const int r = wv * 4 + rr;  /* wave-uniform LDS base, 0..31 */     \
            __builtin_amdgcn_global_load_lds(                                  \
                (const __attribute__((address_space(1))) unsigned int*)        \
                    (gx + (size_t)r * IN + (KC) * 256 + 4 * lane),             \
                (__attribute__((address_space(3))) unsigned int*)              \
                    &xs[(P)][r * 256],                                         \
                16, 0, 0);                                                     \
        }                                                                      \
    }

    // chunk-0 W/B raw loads (one raw copy live; reused as next-chunk prefetch)
    float4 wn[2], bn[2];
#pragma unroll
    for (int j = 0; j < 2; ++j) {
        wn[j] = *(const float4*)&W[(size_t)(n0 + j) * IN + 4 * lane];
        bn[j] = *(const float4*)&B[(size_t)(n0 + j) * IN + 4 * lane];
    }

    float acc[32];   // acc[j*16+bb]: neuron j, batch b0+bb — indices static
#pragma unroll
    for (int i = 0; i < 32; ++i) acc[i] = 0.0f;

    STAGE(0, 0);

    // fold chunk-0 per-(n,k) math: a = x*iv + bs (revolutions, includes +1/8)
    float4 iv[2], bs[2];
#pragma unroll
    for (int j = 0; j < 2; ++j) {
        iv[j].x = INV2PI * __builtin_amdgcn_rcpf(1.0f + fabsf(wn[j].x));
        iv[j].y = INV2PI * __builtin_amdgcn_rcpf(1.0f + fabsf(wn[j].y));
        iv[j].z = INV2PI * __builtin_amdgcn_rcpf(1.0f + fabsf(wn[j].z));
        iv[j].w = INV2PI * __builtin_amdgcn_rcpf(1.0f + fabsf(wn[j].w));
        bs[j].x = fmaf(bn[j].x, INV2PI, 0.125f);
        bs[j].y = fmaf(bn[j].y, INV2PI, 0.125f);
        bs[j].z = fmaf(bn[j].z, INV2PI, 0.125f);
        bs[j].w = fmaf(bn[j].w, INV2PI, 0.125f);
    }
    __syncthreads();   // chunk 0 staged

#pragma unroll 1       // keep code size small; body is bb-unrolled
    for (int kc = 0; kc < 4; ++kc) {
        const int p = kc & 1;

        if (kc < 3) {   // prefetch next W/B chunk (regs) + next x chunk (LDS)
#pragma unroll
            for (int j = 0; j < 2; ++j) {
                wn[j] = *(const float4*)&W[(size_t)(n0 + j) * IN + (kc + 1) * 256 + 4 * lane];
                bn[j] = *(const float4*)&B[(size_t)(n0 + j) * IN + (kc + 1) * 256 + 4 * lane];
            }
            STAGE(kc + 1, 1 - p);
        }

#pragma unroll   // MUST be full: dynamic acc idx -> scratch
        for (int bb = 0; bb < 16; ++bb) {
            const float4 xv = *(const float4*)&xs[p][(b0 + bb) * 256 + 4 * lane];
#pragma unroll
            for (int j = 0; j < 2; ++j) {   // one LDS read serves BOTH neurons
                const float a0 = fmaf(xv.x, iv[j].x, bs[j].x);
                const float a1 = fmaf(xv.y, iv[j].y, bs[j].y);
                const float a2 = fmaf(xv.z, iv[j].z, bs[j].z);
                const float a3 = fmaf(xv.w, iv[j].w, bs[j].w);
                const float t0 = __builtin_amdgcn_sinf(a0);   // sin(2*pi*a)
                const float t1 = __builtin_amdgcn_sinf(a1);
                const float t2 = __builtin_amdgcn_sinf(a2);
                const float t3 = __builtin_amdgcn_sinf(a3);
                acc[j * 16 + bb] += (t0 + t1) + (t2 + t3);
            }
        }
        __syncthreads();   // frees buf p, drains prefetch

        if (kc < 3) {      // convert prefetched raw W/B in place
#pragma unroll
            for (int j = 0; j < 2; ++j) {
                iv[j].x = INV2PI * __builtin_amdgcn_rcpf(1.0f + fabsf(wn[j].x));
                iv[j].y = INV2PI * __builtin_amdgcn_rcpf(1.0f + fabsf(wn[j].y));
                iv[j].z = INV2PI * __builtin_amdgcn_rcpf(1.0f + fabsf(wn[j].z));
                iv[j].w = INV2PI * __builtin_amdgcn_rcpf(1.0f + fabsf(wn[j].w));
                bs[j].x = fmaf(bn[j].x, INV2PI, 0.125f);
                bs[j].y = fmaf(bn[j].y, INV2PI, 0.125f);
                bs[j].z = fmaf(bn[j].z, INV2PI, 0.125f);
                bs[j].w = fmaf(bn[j].w, INV2PI, 0.125f);
            }
        }
    }
#undef STAGE

    // transpose-reduce 32 values over 64 lanes:
    // lane l (<32) ends with acc index l: j = l>>4, bb = l&15
#pragma unroll
    for (int j = 0; j < 32; ++j) acc[j] += __shfl_xor(acc[j], 32, 64);
    butterfly<16>(acc, lane);

    if (lane < 32)
        part[(size_t)(h * 32 + b0 + (lane & 15)) * NN + n0 + (lane >> 4)] =
            acc[0] * SQRT2;
}

// ---------------- Stage 2: projection ----------------
// out[b][o] = sum_n part[b][n] * ow[o][n].  Register outer-product, 8o x 8b
// per wave with SCALAR accumulators; only ONE w-row float4 live at a time:
// live regs = acc 64 + vrow 32 + wo 4 + addr ~10 = ~110.  __launch_bounds__
// (256,1) gives the full register budget. PROVEN ~5us in R3 (absent from
// top-5 at the 45us fill threshold) — do not touch.

__global__ __launch_bounds__(256, 1)
void k_proj(const float* __restrict__ part, const float* __restrict__ ow,
            float* __restrict__ out) {
    const int tid  = threadIdx.x;
    const int lane = tid & 63;
    const int wv   = __builtin_amdgcn_readfirstlane(tid >> 6);
    const int wid  = blockIdx.x * 4 + wv;        // 0..1023
    const int o0   = (wid & 127) * 8;            // 128 o-tiles x 8
    const int b0   = (wid >> 7) * 8;             // 8 b-tiles x 8

    float acc[64];   // acc[o*8+b]
#pragma unroll
    for (int i = 0; i < 64; ++i) acc[i] = 0.0f;

#pragma unroll 1
    for (int it = 0; it < NN / 256; ++it) {      // 8 slabs of 256 n
        const int nb = it * 256 + lane * 4;
        float4 vrow[8];
#pragma unroll
        for (int b = 0; b < 8; ++b)
            vrow[b] = *(const float4*)&part[(size_t)(b0 + b) * NN + nb];
#pragma unroll
        for (int o = 0; o < 8; ++o) {
            const float4 wo = *(const float4*)&ow[(size_t)(o0 + o) * NN + nb];
#pragma unroll
            for (int b = 0; b < 8; ++b) {
                float s = acc[o * 8 + b];
                s = fmaf(wo.x, vrow[b].x, s);
                s = fmaf(wo.y, vrow[b].y, s);
                s = fmaf(wo.z, vrow[b].z, s);
                s = fmaf(wo.w, vrow[b].w, s);
                acc[o * 8 + b] = s;
            }
        }
    }

    // full 64-lane butterfly: lane l ends with acc[l]'s total
    butterfly<32>(acc, lane);

    // l = o*8+b  ->  o = lane>>3, b = lane&7
    out[(size_t)(b0 + (lane & 7)) * OUTF + o0 + (lane >> 3)] = acc[0];
}

extern "C" void kernel_launch(void* const* d_in, const int* in_sizes, int n_in,
                              void* d_out, int out_size, void* d_ws, size_t ws_size,
                              hipStream_t stream) {
    const float* x  = (const float*)d_in[0];
    const float* W  = (const float*)d_in[1];
    const float* B  = (const float*)d_in[2];
    const float* ow = (const float*)d_in[3];
    float* out  = (float*)d_out;
    float* part = (float*)d_ws;    // 512 KB, [b][n]

    k_interf<<<dim3(512), dim3(512), 0, stream>>>(x, W, B, part);
    k_proj  <<<dim3(256), dim3(256), 0, stream>>>(part, ow, out);
}

// Round 5
// 108.409 us; speedup vs baseline: 2.2276x; 1.1317x over previous
//
#include <hip/hip_runtime.h>
#include <math.h>

// Problem sizes (fixed by setup_inputs)
constexpr int BATCH = 64;
constexpr int IN    = 1024;
constexpr int NN    = 2048;   // num_neurons
constexpr int OUTF  = 1024;

constexpr float INV2PI = 0.15915494309189535f;  // 1/(2*pi)
constexpr float SQRT2  = 1.4142135623730951f;

// sin_t + cos_t = sqrt(2)*sin(theta + pi/4); reference LUT-quantizes theta to
// 2pi/4096 steps. We drop the quantization (|err| <= sqrt2*pi/4096 ~ 1.1e-3
// per element -> ~8 absmax on the output vs threshold 26.7), so each element
// is ONE fma + ONE v_sin: a = x*(rcp(1+|W|)/2pi) + (B/2pi + 1/8) [revolutions].

// Butterfly transpose-reduction with COMPILE-TIME trip counts.
template<int M>
__device__ __forceinline__ void butterfly(float* acc, int lane) {
    const bool hi = (lane & M) != 0;
#pragma unroll
    for (int j = 0; j < M; ++j) {
        const float send = hi ? acc[j] : acc[j + M];
        const float recv = __shfl_xor(send, M, 64);
        acc[j] = (hi ? acc[j + M] : acc[j]) + recv;
    }
    if constexpr (M > 1) butterfly<M / 2>(acc, lane);
}

// ---------------- Stage 1: interference ----------------
// REGISTER-BUDGET LEDGER (rounds 1-4, the governing constraint):
//   granted arch-VGPR = 256 / min_waves_per_eu:
//     (2,2)/(2,4) -> 128 granted (R4: confirmed spill-free);
//     (4,4) -> 64 -> acc spills every iter -> 340MB scratch -> 134-142us.
// R4 CONFIRMED this kernel clean: wave = 2 neurons x 16 batches, acc[32],
// one ds_read_b128 feeds 8 sins, waves_per_eu(2,4) -> 128-reg budget,
// hot live ~90 fits, 4 waves/SIMD physically (LDS caps 2 blocks/CU).
// Pipe math/chunk/SIMD: trans 4w x 128sin x 8cyc = 4096 (roof, ~6.8us);
// VALU 2048 overlaps; LDS 3072 cyc/CU under roof. DO NOT TOUCH.

__global__ __launch_bounds__(512)
__attribute__((amdgpu_waves_per_eu(2, 4)))
void k_interf(const float* __restrict__ x, const float* __restrict__ W,
              const float* __restrict__ B, float* __restrict__ part) {
    __shared__ float xs[2][32 * 256];   // double buffer, 2 x 32KB

    const int tid  = threadIdx.x;
    const int lane = tid & 63;
    const int wv   = __builtin_amdgcn_readfirstlane(tid >> 6);   // 0..7
    const int bid  = blockIdx.x;        // 512 blocks
    const int h    = bid & 1;           // batch half (32 rows)
    const int np   = wv & 3;            // neuron-pair within block
    const int hq   = wv >> 2;           // which 16-batch group of the half
    const int n0   = (bid >> 1) * 8 + np * 2;   // 256 n-octets
    const int b0   = hq * 16;           // within the staged 32 rows

    const float* gx = x + (size_t)(h * 32) * IN;   // this block's 32 batch rows

#define STAGE(KC, P)                                                           \
    {                                                                          \
        _Pragma("unroll")                                                      \
        for (int rr = 0; rr < 4; ++rr) {                                       \
            const int r = wv * 4 + rr;  /* wave-uniform LDS base, 0..31 */     \
            __builtin_amdgcn_global_load_lds(                                  \
                (const __attribute__((address_space(1))) unsigned int*)        \
                    (gx + (size_t)r * IN + (KC) * 256 + 4 * lane),             \
                (__attribute__((address_space(3))) unsigned int*)              \
                    &xs[(P)][r * 256],                                         \
                16, 0, 0);                                                     \
        }                                                                      \
    }

    // chunk-0 W/B raw loads (one raw copy live; reused as next-chunk prefetch)
    float4 wn[2], bn[2];
#pragma unroll
    for (int j = 0; j < 2; ++j) {
        wn[j] = *(const float4*)&W[(size_t)(n0 + j) * IN + 4 * lane];
        bn[j] = *(const float4*)&B[(size_t)(n0 + j) * IN + 4 * lane];
    }

    float acc[32];   // acc[j*16+bb]: neuron j, batch b0+bb — indices static
#pragma unroll
    for (int i = 0; i < 32; ++i) acc[i] = 0.0f;

    STAGE(0, 0);

    // fold chunk-0 per-(n,k) math: a = x*iv + bs (revolutions, includes +1/8)
    float4 iv[2], bs[2];
#pragma unroll
    for (int j = 0; j < 2; ++j) {
        iv[j].x = INV2PI * __builtin_amdgcn_rcpf(1.0f + fabsf(wn[j].x));
        iv[j].y = INV2PI * __builtin_amdgcn_rcpf(1.0f + fabsf(wn[j].y));
        iv[j].z = INV2PI * __builtin_amdgcn_rcpf(1.0f + fabsf(wn[j].z));
        iv[j].w = INV2PI * __builtin_amdgcn_rcpf(1.0f + fabsf(wn[j].w));
        bs[j].x = fmaf(bn[j].x, INV2PI, 0.125f);
        bs[j].y = fmaf(bn[j].y, INV2PI, 0.125f);
        bs[j].z = fmaf(bn[j].z, INV2PI, 0.125f);
        bs[j].w = fmaf(bn[j].w, INV2PI, 0.125f);
    }
    __syncthreads();   // chunk 0 staged

#pragma unroll 1       // keep code size small; body is bb-unrolled
    for (int kc = 0; kc < 4; ++kc) {
        const int p = kc & 1;

        if (kc < 3) {   // prefetch next W/B chunk (regs) + next x chunk (LDS)
#pragma unroll
            for (int j = 0; j < 2; ++j) {
                wn[j] = *(const float4*)&W[(size_t)(n0 + j) * IN + (kc + 1) * 256 + 4 * lane];
                bn[j] = *(const float4*)&B[(size_t)(n0 + j) * IN + (kc + 1) * 256 + 4 * lane];
            }
            STAGE(kc + 1, 1 - p);
        }

#pragma unroll   // MUST be full: dynamic acc idx -> scratch
        for (int bb = 0; bb < 16; ++bb) {
            const float4 xv = *(const float4*)&xs[p][(b0 + bb) * 256 + 4 * lane];
#pragma unroll
            for (int j = 0; j < 2; ++j) {   // one LDS read serves BOTH neurons
                const float a0 = fmaf(xv.x, iv[j].x, bs[j].x);
                const float a1 = fmaf(xv.y, iv[j].y, bs[j].y);
                const float a2 = fmaf(xv.z, iv[j].z, bs[j].z);
                const float a3 = fmaf(xv.w, iv[j].w, bs[j].w);
                const float t0 = __builtin_amdgcn_sinf(a0);   // sin(2*pi*a)
                const float t1 = __builtin_amdgcn_sinf(a1);
                const float t2 = __builtin_amdgcn_sinf(a2);
                const float t3 = __builtin_amdgcn_sinf(a3);
                acc[j * 16 + bb] += (t0 + t1) + (t2 + t3);
            }
        }
        __syncthreads();   // frees buf p, drains prefetch

        if (kc < 3) {      // convert prefetched raw W/B in place
#pragma unroll
            for (int j = 0; j < 2; ++j) {
                iv[j].x = INV2PI * __builtin_amdgcn_rcpf(1.0f + fabsf(wn[j].x));
                iv[j].y = INV2PI * __builtin_amdgcn_rcpf(1.0f + fabsf(wn[j].y));
                iv[j].z = INV2PI * __builtin_amdgcn_rcpf(1.0f + fabsf(wn[j].z));
                iv[j].w = INV2PI * __builtin_amdgcn_rcpf(1.0f + fabsf(wn[j].w));
                bs[j].x = fmaf(bn[j].x, INV2PI, 0.125f);
                bs[j].y = fmaf(bn[j].y, INV2PI, 0.125f);
                bs[j].z = fmaf(bn[j].z, INV2PI, 0.125f);
                bs[j].w = fmaf(bn[j].w, INV2PI, 0.125f);
            }
        }
    }
#undef STAGE

    // transpose-reduce 32 values over 64 lanes:
    // lane l (<32) ends with acc index l: j = l>>4, bb = l&15
#pragma unroll
    for (int j = 0; j < 32; ++j) acc[j] += __shfl_xor(acc[j], 32, 64);
    butterfly<16>(acc, lane);

    if (lane < 32)
        part[(size_t)(h * 32 + b0 + (lane & 15)) * NN + n0 + (lane >> 4)] =
            acc[0] * SQRT2;
}

// ---------------- Stage 2: projection ----------------
// ROUND-4 POST-MORTEM: dur regressed 108->122.7 with k_interf proven faster;
// the only other moving part is k_proj, which since R1 ran 1024 waves =
// 1 wave/SIMD (launch_bounds(256,1)) -> ZERO latency hiding; every L2/L3
// load bubble exposed. Residual accounting across R1-R4 puts it at ~20-25us
// vs the ~5us BW floor. Fix: back to the 2048-wave R0 shape (2 waves/SIMD)
// with ledger-safe registers: wave = 4o x 8b, SCALAR acc[32] (R0's float4
// acc[4][8]=128 regs was borderline), waves_per_eu(2,4) -> 128-reg grant,
// live = acc 32 + vrow 32 + wo 4 + addr ~15 = ~85 -> no spill.
// L2 traffic 192MB (~5.6us floor) but latency now overlapped 2-deep.

__global__ __launch_bounds__(256)
__attribute__((amdgpu_waves_per_eu(2, 4)))
void k_proj(const float* __restrict__ part, const float* __restrict__ ow,
            float* __restrict__ out) {
    const int tid  = threadIdx.x;
    const int lane = tid & 63;
    const int wv   = __builtin_amdgcn_readfirstlane(tid >> 6);
    const int wid  = blockIdx.x * 4 + wv;        // 0..2047
    const int o0   = (wid & 255) * 4;            // 256 o-tiles x 4
    const int b0   = (wid >> 8) * 8;             // 8 b-tiles x 8

    float acc[32];   // acc[o*8+b]
#pragma unroll
    for (int i = 0; i < 32; ++i) acc[i] = 0.0f;

#pragma unroll 1
    for (int it = 0; it < NN / 256; ++it) {      // 8 slabs of 256 n
        const int nb = it * 256 + lane * 4;
        float4 vrow[8];
#pragma unroll
        for (int b = 0; b < 8; ++b)
            vrow[b] = *(const float4*)&part[(size_t)(b0 + b) * NN + nb];
#pragma unroll
        for (int o = 0; o < 4; ++o) {
            const float4 wo = *(const float4*)&ow[(size_t)(o0 + o) * NN + nb];
#pragma unroll
            for (int b = 0; b < 8; ++b) {
                float s = acc[o * 8 + b];
                s = fmaf(wo.x, vrow[b].x, s);
                s = fmaf(wo.y, vrow[b].y, s);
                s = fmaf(wo.z, vrow[b].z, s);
                s = fmaf(wo.w, vrow[b].w, s);
                acc[o * 8 + b] = s;
            }
        }
    }

    // transpose-reduce 32 values over 64 lanes: lane l (<32) ends with acc[l]
#pragma unroll
    for (int j = 0; j < 32; ++j) acc[j] += __shfl_xor(acc[j], 32, 64);
    butterfly<16>(acc, lane);

    // l = o*8+b  ->  o = lane>>3 (0..3), b = lane&7
    if (lane < 32)
        out[(size_t)(b0 + (lane & 7)) * OUTF + o0 + (lane >> 3)] = acc[0];
}

extern "C" void kernel_launch(void* const* d_in, const int* in_sizes, int n_in,
                              void* d_out, int out_size, void* d_ws, size_t ws_size,
                              hipStream_t stream) {
    const float* x  = (const float*)d_in[0];
    const float* W  = (const float*)d_in[1];
    const float* B  = (const float*)d_in[2];
    const float* ow = (const float*)d_in[3];
    float* out  = (float*)d_out;
    float* part = (float*)d_ws;    // 512 KB, [b][n]

    k_interf<<<dim3(512), dim3(512), 0, stream>>>(x, W, B, part);
    k_proj  <<<dim3(512), dim3(256), 0, stream>>>(part, ow, out);
}